// Round 12
// baseline (206.311 us; speedup 1.0000x reference)
//
#include <hip/hip_runtime.h>

// Encoding layer, fused, MFMA version. B=32, C=256, K=32, N=4096.
// R12: R9 config (1024 blocks x 128 tok) + within-run PHASE ABLATION:
//   enc_ab1 (staging only) / enc_ab2 (+MFMA-A) / enc_ab3 (+softmax) / enc_main (full, real).
//   Diagnostic round — headline dur_us is inflated by the three diag dispatches.
// ws layout (partial path, floats): wxp[8388608] @0 | wsum[1024] @8388608 | abp4[128] @8389632 | cwh @8389760
// ws layout (fallback,    floats): wx[262144] @0 | wsum[1024] @262144 | abp4[128] @263168 | cwh @263296

#define CC 256
#define KK 32
#define NN 4096
#define CN (CC*NN)
#define TOK 128
#define CHK 32
#define NCH 4

typedef unsigned int u32;
typedef unsigned short u16;
typedef __fp16 half2_t __attribute__((ext_vector_type(2)));
typedef _Float16 f16x8 __attribute__((ext_vector_type(8)));
typedef float f32x4 __attribute__((ext_vector_type(4)));
typedef u32 u32x2 __attribute__((ext_vector_type(2)));

__device__ __forceinline__ u32 pack2(float a, float b) {
    half2_t h = __builtin_amdgcn_cvt_pkrtz(a, b);
    u32 u;
    __builtin_memcpy(&u, &h, 4);
    return u;
}

__device__ __forceinline__ void bar_lgkm() {
    asm volatile("s_waitcnt lgkmcnt(0)" ::: "memory");
    __builtin_amdgcn_s_barrier();
    __builtin_amdgcn_sched_barrier(0);
}

#define STAGE_LOAD(CT) {                                                   \
    const float* xp = x + (size_t)b * CN + n0 + (CT) * CHK + (l & 7) * 4;  \
    _Pragma("unroll")                                                      \
    for (int it = 0; it < 8; ++it) {                                       \
        int ch = it * 32 + w * 8 + (l >> 3);                               \
        sf[it] = *(const float4*)(xp + (size_t)ch * NN);                   \
    }                                                                      \
}
#define STAGE_WRITE() {                                                    \
    float s0 = 0.f, s1 = 0.f, s2 = 0.f, s3 = 0.f;                          \
    int tq = l & 7;                                                        \
    _Pragma("unroll")                                                      \
    for (int it = 0; it < 8; ++it) {                                       \
        int ch = it * 32 + w * 8 + (l >> 3);                               \
        float4 f = sf[it];                                                 \
        s0 += f.x * f.x; s1 += f.y * f.y;                                  \
        s2 += f.z * f.z; s3 += f.w * f.w;                                  \
        u32 u0 = pack2(f.x, f.y), u1 = pack2(f.z, f.w);                    \
        *(uint2*)(&xt[((ch >> 2) * 2 + (tq >> 2)) * 64 +                   \
                      (ch & 3) * 16 + (tq & 3) * 4]) =                     \
            make_uint2(u0, u1);                                            \
    }                                                                      \
    s0 += __shfl_xor(s0, 8); s0 += __shfl_xor(s0, 16); s0 += __shfl_xor(s0, 32); \
    s1 += __shfl_xor(s1, 8); s1 += __shfl_xor(s1, 16); s1 += __shfl_xor(s1, 32); \
    s2 += __shfl_xor(s2, 8); s2 += __shfl_xor(s2, 16); s2 += __shfl_xor(s2, 32); \
    s3 += __shfl_xor(s3, 8); s3 += __shfl_xor(s3, 16); s3 += __shfl_xor(s3, 32); \
    if (l < 8) *(float4*)&swsq[w * 32 + tq * 4] = make_float4(s0, s1, s2, s3); \
}

// ---------------- prep: abp table + fp16 codewords [k][ch] ----------------
__global__ void enc_prep(const float* __restrict__ cw, const float* __restrict__ scale,
                         float* __restrict__ abp4, u16* __restrict__ cwh) {
    int tid = threadIdx.x;
    {
        int k = tid >> 3, p = tid & 7;
        float s = 0.f;
        #pragma unroll
        for (int i = 0; i < 32; ++i) {
            float v = cw[k * 256 + p * 32 + i];
            s += v * v;
        }
        s += __shfl_xor(s, 1);
        s += __shfl_xor(s, 2);
        s += __shfl_xor(s, 4);
        if (p == 0) {
            float A = scale[k];
            abp4[k * 4 + 0] = A;
            abp4[k * 4 + 1] = A * s;
            abp4[k * 4 + 2] = -2.f * A;
            abp4[k * 4 + 3] = 0.f;
        }
    }
    for (int i = 0; i < 32; ++i) {
        int idx = i * 256 + tid;
        union { __fp16 h; u16 u; } cv;
        cv.h = (__fp16)cw[idx];
        cwh[idx] = cv.u;
    }
}

// ---------------- common body, phase-gated by LVL ----------------
// LVL1: staging+barriers+sc/swsq writes. LVL2: +tr_read/MFMA-A. LVL3: +softmax. LVL4: full.
template<int LVL>
__device__ __forceinline__ void enc_body(
    const float* __restrict__ x, const u16* __restrict__ cwh,
    const float* __restrict__ abp4, float* __restrict__ wxp, float* __restrict__ wsum,
    int use_partials) {

    __shared__ u16   xt[8192];
    __shared__ float sc[32 * 33];
    __shared__ u16   w2s[32 * 40];
    __shared__ float swsq[128];

    const int tid = threadIdx.x;
    const int l   = tid & 63;
    const int w   = tid >> 6;
    const int b   = blockIdx.x >> 5;
    const int blk = blockIdx.x & 31;
    const int n0  = blk * TOK;

    f16x8 cwf[8];
    {
        const u16* cp = cwh + ((w >> 1) * 16 + (l & 15)) * 256 + (l >> 4) * 8;
        #pragma unroll
        for (int ks = 0; ks < 8; ++ks)
            cwf[ks] = *(const f16x8*)(cp + ks * 32);
    }
    float Ak[4], Bk[4], Pk[4];
    #pragma unroll
    for (int i = 0; i < 4; ++i) {
        const float* ap = abp4 + ((l & 7) * 4 + i) * 4;
        Ak[i] = ap[0]; Bk[i] = ap[1]; Pk[i] = ap[2];
    }

    f32x4 accb[2][4];
    #pragma unroll
    for (int mt = 0; mt < 2; ++mt)
        #pragma unroll
        for (int nt = 0; nt < 4; ++nt)
            accb[mt][nt] = (f32x4){0.f, 0.f, 0.f, 0.f};
    float wsacc[4] = {0.f, 0.f, 0.f, 0.f};

    const u32 xtbase = (u32)(uintptr_t)(&xt[0]);
    float4 sf[8];

    STAGE_LOAD(0);

    #pragma unroll
    for (int ct = 0; ct < NCH; ++ct) {
        STAGE_WRITE();
        bar_lgkm();

        f32x4 acca = (f32x4){0.f, 0.f, 0.f, 0.f};
        if (LVL >= 2) {
            u32 abase = xtbase + (4 * (l >> 4) + (w & 1)) * 128 + (l & 15) * 8;
            u32x2 rr[16];
            #pragma unroll
            for (int ks = 0; ks < 8; ++ks) {
                asm volatile("ds_read_b64_tr_b16 %0, %1 offset:%2"
                             : "=v"(rr[2 * ks]) : "v"(abase), "i"(ks * 2048));
                asm volatile("ds_read_b64_tr_b16 %0, %1 offset:%2"
                             : "=v"(rr[2 * ks + 1]) : "v"(abase), "i"(ks * 2048 + 256));
            }
            asm volatile("s_waitcnt lgkmcnt(0)");
            __builtin_amdgcn_sched_barrier(0);
            #pragma unroll
            for (int ks = 0; ks < 8; ++ks) {
                union { uint4 u; f16x8 h; } af;
                af.u = make_uint4(rr[2 * ks].x, rr[2 * ks].y, rr[2 * ks + 1].x, rr[2 * ks + 1].y);
                acca = __builtin_amdgcn_mfma_f32_16x16x32_f16(af.h, cwf[ks], acca, 0, 0, 0);
            }
        }

        if (ct < NCH - 1) STAGE_LOAD(ct + 1);

        {
            int trow = (w & 1) * 16 + (l >> 4) * 4;
            int kcol = (w >> 1) * 16 + (l & 15);
            #pragma unroll
            for (int r = 0; r < 4; ++r)
                sc[(trow + r) * 33 + kcol] = acca[r];
        }
        bar_lgkm();   // bar A

        if (LVL >= 3) {
            int t = w * 8 + (l >> 3), s = l & 7;
            float xq = swsq[t] + swsq[32 + t] + swsq[64 + t] + swsq[96 + t];
            float lg[4];
            float m = -3.4e38f;
            #pragma unroll
            for (int i = 0; i < 4; ++i) {
                float xcv = sc[t * 33 + s * 4 + i];
                lg[i] = fmaf(Ak[i], xq, Bk[i]) + Pk[i] * xcv;
                m = fmaxf(m, lg[i]);
            }
            m = fmaxf(m, __shfl_xor(m, 1));
            m = fmaxf(m, __shfl_xor(m, 2));
            m = fmaxf(m, __shfl_xor(m, 4));
            float e[4], ssum = 0.f;
            #pragma unroll
            for (int i = 0; i < 4; ++i) { e[i] = __expf(lg[i] - m); ssum += e[i]; }
            ssum += __shfl_xor(ssum, 1);
            ssum += __shfl_xor(ssum, 2);
            ssum += __shfl_xor(ssum, 4);
            float r = 1.0f / ssum;
            #pragma unroll
            for (int i = 0; i < 4; ++i) {
                float wv = e[i] * r;
                wsacc[i] += wv;
                union { __fp16 h; u16 u; } cv;
                cv.h = (__fp16)wv;
                w2s[(s * 4 + i) * 40 + t] = cv.u;
            }
        }
        bar_lgkm();   // bar B

        if (LVL >= 4) {
            f16x8 wa[2];
            #pragma unroll
            for (int mt = 0; mt < 2; ++mt)
                wa[mt] = *(const f16x8*)&w2s[(mt * 16 + (l & 15)) * 40 + (l >> 4) * 8];
            #pragma unroll
            for (int nt = 0; nt < 4; ++nt) {
                int ch = (w * 4 + nt) * 16 + (l & 15);
                const f16x8 xb = *(const f16x8*)&xt[((ch >> 2) * 2 + (l >> 5)) * 64 +
                                                    (ch & 3) * 16 + ((l >> 4) & 1) * 8];
                #pragma unroll
                for (int mt = 0; mt < 2; ++mt)
                    accb[mt][nt] = __builtin_amdgcn_mfma_f32_16x16x32_f16(wa[mt], xb, accb[mt][nt], 0, 0, 0);
            }
        }
        bar_lgkm();   // bar C
    }

    // epilogue (diags write zeros / pre-memset garbage; real path is LVL4)
    #pragma unroll
    for (int i = 0; i < 4; ++i) {
        float v = wsacc[i];
        v += __shfl_xor(v, 8); v += __shfl_xor(v, 16); v += __shfl_xor(v, 32);
        if (l < 8)
            atomicAdd(&wsum[b * KK + (l & 7) * 4 + i], v);
    }
    if (use_partials) {
        float* dst = wxp + (size_t)blockIdx.x * 8192;
        #pragma unroll
        for (int mt = 0; mt < 2; ++mt)
            #pragma unroll
            for (int nt = 0; nt < 4; ++nt)
                #pragma unroll
                for (int r = 0; r < 4; ++r) {
                    int k  = mt * 16 + (l >> 4) * 4 + r;
                    int ch = (w * 4 + nt) * 16 + (l & 15);
                    dst[k * 256 + ch] = accb[mt][nt][r];
                }
    } else {
        #pragma unroll
        for (int mt = 0; mt < 2; ++mt)
            #pragma unroll
            for (int nt = 0; nt < 4; ++nt)
                #pragma unroll
                for (int r = 0; r < 4; ++r) {
                    int k  = mt * 16 + (l >> 4) * 4 + r;
                    int ch = (w * 4 + nt) * 16 + (l & 15);
                    atomicAdd(&wxp[(size_t)b * 8192 + k * 256 + ch], accb[mt][nt][r]);
                }
    }
}

__global__ __launch_bounds__(256, 3) void enc_ab1(const float* __restrict__ x, const u16* __restrict__ cwh,
    const float* __restrict__ abp4, float* __restrict__ wxp, float* __restrict__ wsum, int up) {
    enc_body<1>(x, cwh, abp4, wxp, wsum, up);
}
__global__ __launch_bounds__(256, 3) void enc_ab2(const float* __restrict__ x, const u16* __restrict__ cwh,
    const float* __restrict__ abp4, float* __restrict__ wxp, float* __restrict__ wsum, int up) {
    enc_body<2>(x, cwh, abp4, wxp, wsum, up);
}
__global__ __launch_bounds__(256, 3) void enc_ab3(const float* __restrict__ x, const u16* __restrict__ cwh,
    const float* __restrict__ abp4, float* __restrict__ wxp, float* __restrict__ wsum, int up) {
    enc_body<3>(x, cwh, abp4, wxp, wsum, up);
}
__global__ __launch_bounds__(256, 3) void enc_main(const float* __restrict__ x, const u16* __restrict__ cwh,
    const float* __restrict__ abp4, float* __restrict__ wxp, float* __restrict__ wsum, int up) {
    enc_body<4>(x, cwh, abp4, wxp, wsum, up);
}

// ---------------- finalize ----------------
__global__ void enc_final_part(const float* __restrict__ wxp, const float* __restrict__ wsum,
                               const float* __restrict__ cw, float* __restrict__ out) {
    int i = blockIdx.x * 256 + threadIdx.x;
    int c = i & 255, k = (i >> 8) & 31, b = i >> 13;
    const float* p = wxp + (size_t)b * 32 * 8192 + k * 256 + c;
    float s = 0.f;
    #pragma unroll
    for (int j = 0; j < 32; ++j) s += p[(size_t)j * 8192];
    out[i] = s - wsum[b * 32 + k] * cw[k * 256 + c];
}
__global__ void enc_final_atomic(const float* __restrict__ wx, const float* __restrict__ wsum,
                                 const float* __restrict__ cw, float* __restrict__ out) {
    int i = blockIdx.x * 256 + threadIdx.x;
    int c = i & 255, k = (i >> 8) & 31, b = i >> 13;
    out[i] = wx[i] - wsum[b * 32 + k] * cw[k * 256 + c];
}

extern "C" void kernel_launch(void* const* d_in, const int* in_sizes, int n_in,
                              void* d_out, int out_size, void* d_ws, size_t ws_size,
                              hipStream_t stream) {
    (void)in_sizes; (void)n_in; (void)out_size;
    const float* x     = (const float*)d_in[0];
    const float* cw    = (const float*)d_in[1];
    const float* scale = (const float*)d_in[2];
    float* out = (float*)d_out;
    float* wsf = (float*)d_ws;

    const size_t need = (size_t)(8388608 + 1024 + 128 + 4096) * 4;
    const int use_partials = (ws_size >= need) ? 1 : 0;

    float *wxp, *wsum, *abp4;
    u16* cwh;
    if (use_partials) {
        wxp  = wsf;
        wsum = wsf + 8388608;
        abp4 = wsf + 8389632;
        cwh  = (u16*)(wsf + 8389760);
    } else {
        wxp  = wsf;
        wsum = wsf + 262144;
        abp4 = wsf + 263168;
        cwh  = (u16*)(wsf + 263296);
    }

    hipLaunchKernelGGL(enc_prep, dim3(1), dim3(256), 0, stream, cw, scale, abp4, cwh);

    // ---- diagnostic ablation dispatches (outputs overwritten below) ----
    hipLaunchKernelGGL(enc_ab1, dim3(1024), dim3(256), 0, stream, x, cwh, abp4, wxp, wsum, use_partials);
    hipLaunchKernelGGL(enc_ab2, dim3(1024), dim3(256), 0, stream, x, cwh, abp4, wxp, wsum, use_partials);
    hipLaunchKernelGGL(enc_ab3, dim3(1024), dim3(256), 0, stream, x, cwh, abp4, wxp, wsum, use_partials);

    // ---- reset accumulators, then the real pipeline ----
    if (use_partials)
        (void)hipMemsetAsync(wsum, 0, 1024 * sizeof(float), stream);
    else
        (void)hipMemsetAsync(d_ws, 0, 263168 * sizeof(float), stream);

    hipLaunchKernelGGL(enc_main, dim3(1024), dim3(256), 0, stream, x, cwh, abp4, wxp, wsum, use_partials);
    if (use_partials)
        hipLaunchKernelGGL(enc_final_part,   dim3(1024), dim3(256), 0, stream, wxp, wsum, cw, out);
    else
        hipLaunchKernelGGL(enc_final_atomic, dim3(1024), dim3(256), 0, stream, wxp, wsum, cw, out);
}

// Round 13
// 112.668 us; speedup vs baseline: 1.8311x; 1.8311x over previous
//
#include <hip/hip_runtime.h>

// Encoding layer, fused, MFMA version. B=32, C=256, K=32, N=4096.
// R13: barrier-minimal redesign. 2 barriers/chunk. Swapped-operand MFMA-A
//      (S[k][t], token = lane-col) -> in-register softmax; per-wave-private
//      P buffer (no barrier); pass B computes wx^T[ch][k] per-wave ch-tiles.
// ws layout (partial path, floats): wxpT[8388608] @0 | wsum[1024] @8388608 | abp4[128] @8389632 | cwh @8389760
// ws layout (fallback,    floats): wx[262144] @0 | wsum[1024] @262144 | abp4[128] @263168 | cwh @263296

#define CC 256
#define KK 32
#define NN 4096
#define CN (CC*NN)
#define TOK 128
#define CHK 32
#define NCH 4

typedef unsigned int u32;
typedef unsigned short u16;
typedef __fp16 half2_t __attribute__((ext_vector_type(2)));
typedef _Float16 f16x8 __attribute__((ext_vector_type(8)));
typedef float f32x4 __attribute__((ext_vector_type(4)));
typedef u32 u32x2 __attribute__((ext_vector_type(2)));

__device__ __forceinline__ u32 pack2(float a, float b) {
    half2_t h = __builtin_amdgcn_cvt_pkrtz(a, b);
    u32 u;
    __builtin_memcpy(&u, &h, 4);
    return u;
}

__device__ __forceinline__ void bar_lgkm() {
    asm volatile("s_waitcnt lgkmcnt(0)" ::: "memory");
    __builtin_amdgcn_s_barrier();
    __builtin_amdgcn_sched_barrier(0);
}

#define STAGE_LOAD(CT) {                                                   \
    const float* xp = x + (size_t)b * CN + n0 + (CT) * CHK + (l & 7) * 4;  \
    _Pragma("unroll")                                                      \
    for (int it = 0; it < 8; ++it) {                                       \
        int ch = it * 32 + w * 8 + (l >> 3);                               \
        sf[it] = *(const float4*)(xp + (size_t)ch * NN);                   \
    }                                                                      \
}
#define STAGE_WRITE() {                                                    \
    float s0 = 0.f, s1 = 0.f, s2 = 0.f, s3 = 0.f;                          \
    int tq = l & 7;                                                        \
    _Pragma("unroll")                                                      \
    for (int it = 0; it < 8; ++it) {                                       \
        int ch = it * 32 + w * 8 + (l >> 3);                               \
        float4 f = sf[it];                                                 \
        s0 += f.x * f.x; s1 += f.y * f.y;                                  \
        s2 += f.z * f.z; s3 += f.w * f.w;                                  \
        u32 u0 = pack2(f.x, f.y), u1 = pack2(f.z, f.w);                    \
        *(uint2*)(&xt[((ch >> 2) * 2 + (tq >> 2)) * 64 +                   \
                      (ch & 3) * 16 + (tq & 3) * 4]) =                     \
            make_uint2(u0, u1);                                            \
    }                                                                      \
    s0 += __shfl_xor(s0, 8); s0 += __shfl_xor(s0, 16); s0 += __shfl_xor(s0, 32); \
    s1 += __shfl_xor(s1, 8); s1 += __shfl_xor(s1, 16); s1 += __shfl_xor(s1, 32); \
    s2 += __shfl_xor(s2, 8); s2 += __shfl_xor(s2, 16); s2 += __shfl_xor(s2, 32); \
    s3 += __shfl_xor(s3, 8); s3 += __shfl_xor(s3, 16); s3 += __shfl_xor(s3, 32); \
    if (l < 8) *(float4*)&swsq[w * 32 + tq * 4] = make_float4(s0, s1, s2, s3); \
}

// ---------------- prep: abp table + fp16 codewords [k][ch] ----------------
__global__ void enc_prep(const float* __restrict__ cw, const float* __restrict__ scale,
                         float* __restrict__ abp4, u16* __restrict__ cwh) {
    int tid = threadIdx.x;
    {
        int k = tid >> 3, p = tid & 7;
        float s = 0.f;
        #pragma unroll
        for (int i = 0; i < 32; ++i) {
            float v = cw[k * 256 + p * 32 + i];
            s += v * v;
        }
        s += __shfl_xor(s, 1);
        s += __shfl_xor(s, 2);
        s += __shfl_xor(s, 4);
        if (p == 0) {
            float A = scale[k];
            abp4[k * 4 + 0] = A;
            abp4[k * 4 + 1] = A * s;
            abp4[k * 4 + 2] = -2.f * A;
            abp4[k * 4 + 3] = 0.f;
        }
    }
    for (int i = 0; i < 32; ++i) {
        int idx = i * 256 + tid;
        union { __fp16 h; u16 u; } cv;
        cv.h = (__fp16)cw[idx];
        cwh[idx] = cv.u;
    }
}

// pass-A issue: 4 tr_reads (X B-frags, both token-tiles) + 2 cw global loads (both k-tiles)
#define PA_ISSUE(KS, P) {                                                        \
    asm volatile("ds_read_b64_tr_b16 %0, %1 offset:%2"                           \
                 : "=v"(trA[P][0]) : "v"(ab0), "i"((KS) * 2048));                \
    asm volatile("ds_read_b64_tr_b16 %0, %1 offset:%2"                           \
                 : "=v"(trA[P][1]) : "v"(ab0), "i"((KS) * 2048 + 256));          \
    asm volatile("ds_read_b64_tr_b16 %0, %1 offset:%2"                           \
                 : "=v"(trA[P][2]) : "v"(ab1), "i"((KS) * 2048));                \
    asm volatile("ds_read_b64_tr_b16 %0, %1 offset:%2"                           \
                 : "=v"(trA[P][3]) : "v"(ab1), "i"((KS) * 2048 + 256));          \
    cwR[P][0] = *(const uint4*)(cwg + (KS) * 16);                                \
    cwR[P][1] = *(const uint4*)(cwg + 2048 + (KS) * 16);                         \
}

// ---------------- fused main: 1024 blocks x 256 threads, 128 tokens each ----------------
__global__ __launch_bounds__(256, 2) void enc_main(
    const float* __restrict__ x, const u16* __restrict__ cwh,
    const float* __restrict__ abp4, float* __restrict__ wxp, float* __restrict__ wsum,
    int use_partials) {

    __shared__ u16   xt[8192];        // 16 KB, ch-major subtiled (R9 layout)
    __shared__ u16   w2sp[4][1024];   // per-wave-private P [k][t], stride 32
    __shared__ float swsq[128];       // [wave][32] xsq partials

    const int tid = threadIdx.x;
    const int l   = tid & 63;
    const int w   = tid >> 6;
    const int b   = blockIdx.x >> 5;
    const int blk = blockIdx.x & 31;
    const int n0  = blk * TOK;
    const int lg  = (l >> 4) & 3;

    // softmax per-k constants: lane's k = Mt*16 + lg*4 + r
    float Ak[2][4], Bk[2][4], Pk[2][4];
    #pragma unroll
    for (int Mt = 0; Mt < 2; ++Mt)
        #pragma unroll
        for (int r = 0; r < 4; ++r) {
            const float* ap = abp4 + (Mt * 16 + lg * 4 + r) * 4;
            Ak[Mt][r] = ap[0]; Bk[Mt][r] = ap[1]; Pk[Mt][r] = ap[2];
        }

    // cw gather base (u32 units): cwh[(Mt*16 + l&15)*256 + ks*32 + lg*8]
    const u32* cwg = (const u32*)cwh + (l & 15) * 128 + lg * 4;

    f32x4 accb[4][2];   // [ch-tile q][k-tile Nk]
    #pragma unroll
    for (int q = 0; q < 4; ++q)
        #pragma unroll
        for (int nk = 0; nk < 2; ++nk)
            accb[q][nk] = (f32x4){0.f, 0.f, 0.f, 0.f};
    float wsacc[2][4];
    #pragma unroll
    for (int Mt = 0; Mt < 2; ++Mt)
        #pragma unroll
        for (int r = 0; r < 4; ++r) wsacc[Mt][r] = 0.f;

    const u32 xtbase = (u32)(uintptr_t)(&xt[0]);
    const u32 ab0 = xtbase + (4 * (l >> 4)) * 128 + (l & 15) * 8;   // token-tile 0
    const u32 ab1 = ab0 + 128;                                       // token-tile 1
    float4 sf[8];

    STAGE_LOAD(0);

    #pragma unroll
    for (int ct = 0; ct < NCH; ++ct) {
        STAGE_WRITE();
        bar_lgkm();               // bar 1: xt + swsq ready

        // ---- pass A: S[k][t] = Cw·X^T, 1-deep pipelined reads ----
        f32x4 acca[2][2];
        #pragma unroll
        for (int Mt = 0; Mt < 2; ++Mt)
            #pragma unroll
            for (int Nt = 0; Nt < 2; ++Nt)
                acca[Mt][Nt] = (f32x4){0.f, 0.f, 0.f, 0.f};
        {
            u32x2 trA[2][4];
            uint4 cwR[2][2];
            PA_ISSUE(0, 0);
            #pragma unroll
            for (int ks = 0; ks < 8; ++ks) {
                const int p = ks & 1;
                if (ks < 7) {
                    if (p == 0) { PA_ISSUE(ks + 1, 1); }
                    else        { PA_ISSUE(ks + 1, 0); }
                    asm volatile("s_waitcnt lgkmcnt(4)");
                } else {
                    asm volatile("s_waitcnt lgkmcnt(0)");
                }
                __builtin_amdgcn_sched_barrier(0);
                #pragma unroll
                for (int Nt = 0; Nt < 2; ++Nt) {
                    union { uint4 u; f16x8 h; } af;
                    af.u = make_uint4(trA[p][2 * Nt].x, trA[p][2 * Nt].y,
                                      trA[p][2 * Nt + 1].x, trA[p][2 * Nt + 1].y);
                    #pragma unroll
                    for (int Mt = 0; Mt < 2; ++Mt) {
                        union { uint4 u; f16x8 h; } cf;
                        cf.u = cwR[p][Mt];
                        acca[Mt][Nt] = __builtin_amdgcn_mfma_f32_16x16x32_f16(
                            cf.h, af.h, acca[Mt][Nt], 0, 0, 0);
                    }
                }
            }
        }

        // ---- issue next-chunk global loads (in flight across bar 2) ----
        if (ct < NCH - 1) STAGE_LOAD(ct + 1);

        // ---- in-register softmax (token t = Nt*16 + (l&15), k spread over lg + regs) ----
        {
            float xq[2];
            #pragma unroll
            for (int Nt = 0; Nt < 2; ++Nt) {
                int t = Nt * 16 + (l & 15);
                xq[Nt] = swsq[t] + swsq[32 + t] + swsq[64 + t] + swsq[96 + t];
            }
            #pragma unroll
            for (int Nt = 0; Nt < 2; ++Nt) {
                float lgt[2][4];
                float m = -3.4e38f;
                #pragma unroll
                for (int Mt = 0; Mt < 2; ++Mt)
                    #pragma unroll
                    for (int r = 0; r < 4; ++r) {
                        lgt[Mt][r] = fmaf(Ak[Mt][r], xq[Nt], Bk[Mt][r]) + Pk[Mt][r] * acca[Mt][Nt][r];
                        m = fmaxf(m, lgt[Mt][r]);
                    }
                m = fmaxf(m, __shfl_xor(m, 16));
                m = fmaxf(m, __shfl_xor(m, 32));
                float s = 0.f, e[2][4];
                #pragma unroll
                for (int Mt = 0; Mt < 2; ++Mt)
                    #pragma unroll
                    for (int r = 0; r < 4; ++r) { e[Mt][r] = __expf(lgt[Mt][r] - m); s += e[Mt][r]; }
                s += __shfl_xor(s, 16);
                s += __shfl_xor(s, 32);
                float rcp = 1.0f / s;
                #pragma unroll
                for (int Mt = 0; Mt < 2; ++Mt)
                    #pragma unroll
                    for (int r = 0; r < 4; ++r) {
                        float wv = e[Mt][r] * rcp;
                        wsacc[Mt][r] += wv;
                        union { __fp16 h; u16 u; } cv;
                        cv.h = (__fp16)wv;
                        w2sp[w][(Mt * 16 + lg * 4 + r) * 32 + Nt * 16 + (l & 15)] = cv.u;
                    }
            }
        }
        // compiler orders w2sp write->read via lgkmcnt (same wave, same array)

        // ---- pass B: wx^T[ch][k] += X^T·P^T over the chunk's 32 tokens ----
        {
            f16x8 pB[2];
            #pragma unroll
            for (int nk = 0; nk < 2; ++nk)
                pB[nk] = *(const f16x8*)&w2sp[w][(nk * 16 + (l & 15)) * 32 + lg * 8];
            #pragma unroll
            for (int q = 0; q < 4; ++q) {
                int ch = (w * 4 + q) * 16 + (l & 15);
                const f16x8 xA = *(const f16x8*)&xt[((ch >> 2) * 2 + (l >> 5)) * 64 +
                                                    (ch & 3) * 16 + ((l >> 4) & 1) * 8];
                #pragma unroll
                for (int nk = 0; nk < 2; ++nk)
                    accb[q][nk] = __builtin_amdgcn_mfma_f32_16x16x32_f16(xA, pB[nk], accb[q][nk], 0, 0, 0);
            }
        }
        bar_lgkm();               // bar 2: xt consumed; next stage may overwrite
    }

    // ---- epilogue: wsum (wave 0 only; redundant copies elsewhere) ----
    #pragma unroll
    for (int Mt = 0; Mt < 2; ++Mt)
        #pragma unroll
        for (int r = 0; r < 4; ++r) {
            float v = wsacc[Mt][r];
            v += __shfl_xor(v, 1); v += __shfl_xor(v, 2);
            v += __shfl_xor(v, 4); v += __shfl_xor(v, 8);
            if (w == 0 && (l & 15) == 0)
                atomicAdd(&wsum[b * KK + Mt * 16 + lg * 4 + r], v);
        }
    // ---- wx^T partial stores: wxpT[block][ch][k] ----
    if (use_partials) {
        float* dst = wxp + (size_t)blockIdx.x * 8192;
        #pragma unroll
        for (int q = 0; q < 4; ++q)
            #pragma unroll
            for (int nk = 0; nk < 2; ++nk)
                #pragma unroll
                for (int r = 0; r < 4; ++r) {
                    int ch = (w * 4 + q) * 16 + lg * 4 + r;
                    int k  = nk * 16 + (l & 15);
                    dst[ch * 32 + k] = accb[q][nk][r];
                }
    } else {
        #pragma unroll
        for (int q = 0; q < 4; ++q)
            #pragma unroll
            for (int nk = 0; nk < 2; ++nk)
                #pragma unroll
                for (int r = 0; r < 4; ++r) {
                    int ch = (w * 4 + q) * 16 + lg * 4 + r;
                    int k  = nk * 16 + (l & 15);
                    atomicAdd(&wxp[(size_t)b * 8192 + k * 256 + ch], accb[q][nk][r]);
                }
    }
}

// ---------------- finalize (partial path): out[b][k][c] = sum_j wxpT[b*32+j][c][k] - wsum*c ----
__global__ void enc_final_part(const float* __restrict__ wxp, const float* __restrict__ wsum,
                               const float* __restrict__ cw, float* __restrict__ out) {
    int i = blockIdx.x * 256 + threadIdx.x;
    int c = i & 255, k = (i >> 8) & 31, b = i >> 13;
    const float* p = wxp + (size_t)b * 32 * 8192 + c * 32 + k;
    float s = 0.f;
    #pragma unroll
    for (int j = 0; j < 32; ++j) s += p[(size_t)j * 8192];
    out[i] = s - wsum[b * 32 + k] * cw[k * 256 + c];
}
__global__ void enc_final_atomic(const float* __restrict__ wx, const float* __restrict__ wsum,
                                 const float* __restrict__ cw, float* __restrict__ out) {
    int i = blockIdx.x * 256 + threadIdx.x;
    int c = i & 255, k = (i >> 8) & 31, b = i >> 13;
    out[i] = wx[i] - wsum[b * 32 + k] * cw[k * 256 + c];
}

extern "C" void kernel_launch(void* const* d_in, const int* in_sizes, int n_in,
                              void* d_out, int out_size, void* d_ws, size_t ws_size,
                              hipStream_t stream) {
    (void)in_sizes; (void)n_in; (void)out_size;
    const float* x     = (const float*)d_in[0];
    const float* cw    = (const float*)d_in[1];
    const float* scale = (const float*)d_in[2];
    float* out = (float*)d_out;
    float* wsf = (float*)d_ws;

    const size_t need = (size_t)(8388608 + 1024 + 128 + 4096) * 4;
    const int use_partials = (ws_size >= need) ? 1 : 0;

    float *wxp, *wsum, *abp4;
    u16* cwh;
    if (use_partials) {
        wxp  = wsf;                        // 8388608 f32 (1024 block tiles, [ch][k])
        wsum = wsf + 8388608;              // 1024 f32
        abp4 = wsf + 8389632;              // 128 f32
        cwh  = (u16*)(wsf + 8389760);      // 8192 u16
        (void)hipMemsetAsync(wsum, 0, 1024 * sizeof(float), stream);
    } else {
        wxp  = wsf;                        // 262144 f32
        wsum = wsf + 262144;               // 1024 f32
        abp4 = wsf + 263168;               // 128 f32
        cwh  = (u16*)(wsf + 263296);       // 8192 u16
        (void)hipMemsetAsync(d_ws, 0, 263168 * sizeof(float), stream);
    }

    hipLaunchKernelGGL(enc_prep, dim3(1),    dim3(256), 0, stream, cw, scale, abp4, cwh);
    hipLaunchKernelGGL(enc_main, dim3(1024), dim3(256), 0, stream, x, cwh, abp4, wxp, wsum, use_partials);
    if (use_partials)
        hipLaunchKernelGGL(enc_final_part,   dim3(1024), dim3(256), 0, stream, wxp, wsum, cw, out);
    else
        hipLaunchKernelGGL(enc_final_atomic, dim3(1024), dim3(256), 0, stream, wxp, wsum, cw, out);
}

// Round 14
// 48.636 us; speedup vs baseline: 4.2419x; 2.3166x over previous
//
#include <hip/hip_runtime.h>

// Encoding layer, fused, MFMA version. B=32, C=256, K=32, N=4096.
// R14: R13 fixed. cw A-frags preloaded to 64 VGPRs (no per-ks global loads);
//      ONE barrier/chunk via double-buffered xt+swsq; 512 blocks x 256 tok x 8 chunks;
//      enc_final reads coalesced (k-fastest thread map).
// ws (partial path, floats): wxpT[512*8192] @0 | wsum[1024] @4194304 | abp4[128] @4195328 | cwh @4195456
// ws (fallback,    floats): wx[262144] @0 | wsum[1024] @262144 | abp4[128] @263168 | cwh @263296

#define CC 256
#define KK 32
#define NN 4096
#define CN (CC*NN)
#define TOK 256
#define CHK 32
#define NCH 8

typedef unsigned int u32;
typedef unsigned short u16;
typedef __fp16 half2_t __attribute__((ext_vector_type(2)));
typedef _Float16 f16x8 __attribute__((ext_vector_type(8)));
typedef float f32x4 __attribute__((ext_vector_type(4)));
typedef u32 u32x2 __attribute__((ext_vector_type(2)));

__device__ __forceinline__ u32 pack2(float a, float b) {
    half2_t h = __builtin_amdgcn_cvt_pkrtz(a, b);
    u32 u;
    __builtin_memcpy(&u, &h, 4);
    return u;
}

__device__ __forceinline__ void bar_lgkm() {
    asm volatile("s_waitcnt lgkmcnt(0)" ::: "memory");
    __builtin_amdgcn_s_barrier();
    __builtin_amdgcn_sched_barrier(0);
}

// stage chunk CT's 32 tokens x 256 ch (per thread: 8 float4)
#define STAGE_LOAD(CT) {                                                     \
    const float* xp = x + (size_t)b * CN + n0 + (CT) * CHK + (l & 7) * 4;    \
    _Pragma("unroll")                                                        \
    for (int it = 0; it < 8; ++it) {                                         \
        int ch = it * 32 + w * 8 + (l >> 3);                                 \
        sf[it] = *(const float4*)(xp + (size_t)ch * NN);                     \
    }                                                                        \
}
#define STAGE_WRITE(XTB, SQB) {                                              \
    float s0 = 0.f, s1 = 0.f, s2 = 0.f, s3 = 0.f;                            \
    int tq = l & 7;                                                          \
    _Pragma("unroll")                                                        \
    for (int it = 0; it < 8; ++it) {                                         \
        int ch = it * 32 + w * 8 + (l >> 3);                                 \
        float4 f = sf[it];                                                   \
        s0 += f.x * f.x; s1 += f.y * f.y;                                    \
        s2 += f.z * f.z; s3 += f.w * f.w;                                    \
        u32 u0 = pack2(f.x, f.y), u1 = pack2(f.z, f.w);                      \
        *(uint2*)(&(XTB)[((ch >> 2) * 2 + (tq >> 2)) * 64 +                  \
                         (ch & 3) * 16 + (tq & 3) * 4]) =                    \
            make_uint2(u0, u1);                                              \
    }                                                                        \
    s0 += __shfl_xor(s0, 8); s0 += __shfl_xor(s0, 16); s0 += __shfl_xor(s0, 32); \
    s1 += __shfl_xor(s1, 8); s1 += __shfl_xor(s1, 16); s1 += __shfl_xor(s1, 32); \
    s2 += __shfl_xor(s2, 8); s2 += __shfl_xor(s2, 16); s2 += __shfl_xor(s2, 32); \
    s3 += __shfl_xor(s3, 8); s3 += __shfl_xor(s3, 16); s3 += __shfl_xor(s3, 32); \
    if (l < 8) *(float4*)&(SQB)[w * 32 + tq * 4] = make_float4(s0, s1, s2, s3);  \
}

// ---------------- prep: abp table + fp16 codewords [k][ch] ----------------
__global__ void enc_prep(const float* __restrict__ cw, const float* __restrict__ scale,
                         float* __restrict__ abp4, u16* __restrict__ cwh) {
    int tid = threadIdx.x;
    {
        int k = tid >> 3, p = tid & 7;
        float s = 0.f;
        #pragma unroll
        for (int i = 0; i < 32; ++i) {
            float v = cw[k * 256 + p * 32 + i];
            s += v * v;
        }
        s += __shfl_xor(s, 1);
        s += __shfl_xor(s, 2);
        s += __shfl_xor(s, 4);
        if (p == 0) {
            float A = scale[k];
            abp4[k * 4 + 0] = A;
            abp4[k * 4 + 1] = A * s;
            abp4[k * 4 + 2] = -2.f * A;
            abp4[k * 4 + 3] = 0.f;
        }
    }
    for (int i = 0; i < 32; ++i) {
        int idx = i * 256 + tid;
        union { __fp16 h; u16 u; } cv;
        cv.h = (__fp16)cw[idx];
        cwh[idx] = cv.u;
    }
}

#define PA_ISSUE(KS, P, A0, A1) {                                                \
    asm volatile("ds_read_b64_tr_b16 %0, %1 offset:%2"                           \
                 : "=v"(trA[P][0]) : "v"(A0), "i"((KS) * 2048));                 \
    asm volatile("ds_read_b64_tr_b16 %0, %1 offset:%2"                           \
                 : "=v"(trA[P][1]) : "v"(A0), "i"((KS) * 2048 + 256));           \
    asm volatile("ds_read_b64_tr_b16 %0, %1 offset:%2"                           \
                 : "=v"(trA[P][2]) : "v"(A1), "i"((KS) * 2048));                 \
    asm volatile("ds_read_b64_tr_b16 %0, %1 offset:%2"                           \
                 : "=v"(trA[P][3]) : "v"(A1), "i"((KS) * 2048 + 256));           \
}

// ---------------- fused main: 512 blocks x 256 threads, 256 tokens each ----------------
__global__ __launch_bounds__(256, 2) void enc_main(
    const float* __restrict__ x, const u16* __restrict__ cwh,
    const float* __restrict__ abp4, float* __restrict__ wxp, float* __restrict__ wsum,
    int use_partials) {

    __shared__ u16   xt[2][8192];     // 2 x 16 KB, double buffer (chunk parity)
    __shared__ u16   w2sp[4][1024];   // per-wave-private P [k][t]
    __shared__ float swsq[2][128];    // xsq partials, double buffer

    const int tid = threadIdx.x;
    const int l   = tid & 63;
    const int w   = tid >> 6;
    const int b   = blockIdx.x >> 4;
    const int blk = blockIdx.x & 15;
    const int n0  = blk * TOK;
    const int lg  = (l >> 4) & 3;

    // cw A-frags, preloaded ONCE: cwA[ks][Mt] (64 VGPRs), L2-warm source
    uint4 cwA[8][2];
    {
        const u32* cwg = (const u32*)cwh + (l & 15) * 128 + lg * 4;
        #pragma unroll
        for (int ks = 0; ks < 8; ++ks) {
            cwA[ks][0] = *(const uint4*)(cwg + ks * 16);
            cwA[ks][1] = *(const uint4*)(cwg + 2048 + ks * 16);
        }
    }
    // softmax per-k constants: lane's k = Mt*16 + lg*4 + r
    float Ak[2][4], Bk[2][4], Pk[2][4];
    #pragma unroll
    for (int Mt = 0; Mt < 2; ++Mt)
        #pragma unroll
        for (int r = 0; r < 4; ++r) {
            const float* ap = abp4 + (Mt * 16 + lg * 4 + r) * 4;
            Ak[Mt][r] = ap[0]; Bk[Mt][r] = ap[1]; Pk[Mt][r] = ap[2];
        }

    f32x4 accb[4][2];   // [ch-tile q][k-tile nk]
    #pragma unroll
    for (int q = 0; q < 4; ++q)
        #pragma unroll
        for (int nk = 0; nk < 2; ++nk)
            accb[q][nk] = (f32x4){0.f, 0.f, 0.f, 0.f};
    float wsacc[2][4];
    #pragma unroll
    for (int Mt = 0; Mt < 2; ++Mt)
        #pragma unroll
        for (int r = 0; r < 4; ++r) wsacc[Mt][r] = 0.f;

    float4 sf[8];

    STAGE_LOAD(0);

    for (int ct = 0; ct < NCH; ++ct) {
        const int p2 = ct & 1;
        u16* xtb = &xt[p2][0];
        float* sqb = &swsq[p2][0];

        STAGE_WRITE(xtb, sqb);
        bar_lgkm();               // the ONLY barrier per chunk

        const u32 a0 = (u32)(uintptr_t)xtb + (4 * (l >> 4)) * 128 + (l & 15) * 8;
        const u32 a1 = a0 + 128;

        // ---- pass A: S[k][t] = Cw·X^T (cw frags in regs, tr_reads 1-deep) ----
        f32x4 acca[2][2];
        #pragma unroll
        for (int Mt = 0; Mt < 2; ++Mt)
            #pragma unroll
            for (int Nt = 0; Nt < 2; ++Nt)
                acca[Mt][Nt] = (f32x4){0.f, 0.f, 0.f, 0.f};
        {
            u32x2 trA[2][4];
            PA_ISSUE(0, 0, a0, a1);
            #pragma unroll
            for (int ks = 0; ks < 8; ++ks) {
                const int p = ks & 1;
                if (ks < 7) {
                    if (p == 0) { PA_ISSUE(ks + 1, 1, a0, a1); }
                    else        { PA_ISSUE(ks + 1, 0, a0, a1); }
                    asm volatile("s_waitcnt lgkmcnt(4)");
                } else {
                    asm volatile("s_waitcnt lgkmcnt(0)");
                }
                __builtin_amdgcn_sched_barrier(0);
                #pragma unroll
                for (int Nt = 0; Nt < 2; ++Nt) {
                    union { uint4 u; f16x8 h; } af;
                    af.u = make_uint4(trA[p][2 * Nt].x, trA[p][2 * Nt].y,
                                      trA[p][2 * Nt + 1].x, trA[p][2 * Nt + 1].y);
                    #pragma unroll
                    for (int Mt = 0; Mt < 2; ++Mt) {
                        union { uint4 u; f16x8 h; } cf;
                        cf.u = cwA[ks][Mt];
                        acca[Mt][Nt] = __builtin_amdgcn_mfma_f32_16x16x32_f16(
                            cf.h, af.h, acca[Mt][Nt], 0, 0, 0);
                    }
                }
            }
        }

        // ---- issue next-chunk global loads (no barrier crossing until next STAGE_WRITE) ----
        if (ct < NCH - 1) STAGE_LOAD(ct + 1);

        // ---- in-register softmax (token t = Nt*16 + (l&15)) ----
        {
            #pragma unroll
            for (int Nt = 0; Nt < 2; ++Nt) {
                int t = Nt * 16 + (l & 15);
                float xq = sqb[t] + sqb[32 + t] + sqb[64 + t] + sqb[96 + t];
                float lgt[2][4];
                float m = -3.4e38f;
                #pragma unroll
                for (int Mt = 0; Mt < 2; ++Mt)
                    #pragma unroll
                    for (int r = 0; r < 4; ++r) {
                        lgt[Mt][r] = fmaf(Ak[Mt][r], xq, Bk[Mt][r]) + Pk[Mt][r] * acca[Mt][Nt][r];
                        m = fmaxf(m, lgt[Mt][r]);
                    }
                m = fmaxf(m, __shfl_xor(m, 16));
                m = fmaxf(m, __shfl_xor(m, 32));
                float s = 0.f, e[2][4];
                #pragma unroll
                for (int Mt = 0; Mt < 2; ++Mt)
                    #pragma unroll
                    for (int r = 0; r < 4; ++r) { e[Mt][r] = __expf(lgt[Mt][r] - m); s += e[Mt][r]; }
                s += __shfl_xor(s, 16);
                s += __shfl_xor(s, 32);
                float rcp = 1.0f / s;
                #pragma unroll
                for (int Mt = 0; Mt < 2; ++Mt)
                    #pragma unroll
                    for (int r = 0; r < 4; ++r) {
                        float wv = e[Mt][r] * rcp;
                        wsacc[Mt][r] += wv;
                        union { __fp16 h; u16 u; } cv;
                        cv.h = (__fp16)wv;
                        w2sp[w][(Mt * 16 + lg * 4 + r) * 32 + Nt * 16 + (l & 15)] = cv.u;
                    }
            }
        }
        // w2sp same-wave write->read ordered by compiler-inserted lgkmcnt

        // ---- pass B: wx^T[ch][k] += X^T·P^T ----
        {
            f16x8 pB[2];
            #pragma unroll
            for (int nk = 0; nk < 2; ++nk)
                pB[nk] = *(const f16x8*)&w2sp[w][(nk * 16 + (l & 15)) * 32 + lg * 8];
            #pragma unroll
            for (int q = 0; q < 4; ++q) {
                int ch = (w * 4 + q) * 16 + (l & 15);
                const f16x8 xA = *(const f16x8*)&xtb[((ch >> 2) * 2 + (l >> 5)) * 64 +
                                                     (ch & 3) * 16 + ((l >> 4) & 1) * 8];
                #pragma unroll
                for (int nk = 0; nk < 2; ++nk)
                    accb[q][nk] = __builtin_amdgcn_mfma_f32_16x16x32_f16(xA, pB[nk], accb[q][nk], 0, 0, 0);
            }
        }
        // no trailing barrier: next STAGE_WRITE targets the other buffer
    }

    // ---- epilogue: wsum (wave 0 counts each token once) ----
    #pragma unroll
    for (int Mt = 0; Mt < 2; ++Mt)
        #pragma unroll
        for (int r = 0; r < 4; ++r) {
            float v = wsacc[Mt][r];
            v += __shfl_xor(v, 1); v += __shfl_xor(v, 2);
            v += __shfl_xor(v, 4); v += __shfl_xor(v, 8);
            if (w == 0 && (l & 15) == 0)
                atomicAdd(&wsum[b * KK + Mt * 16 + lg * 4 + r], v);
        }
    // ---- wx^T partial stores: wxpT[block][ch][k] (k = l&15 -> 64B runs) ----
    if (use_partials) {
        float* dst = wxp + (size_t)blockIdx.x * 8192;
        #pragma unroll
        for (int q = 0; q < 4; ++q)
            #pragma unroll
            for (int nk = 0; nk < 2; ++nk)
                #pragma unroll
                for (int r = 0; r < 4; ++r) {
                    int ch = (w * 4 + q) * 16 + lg * 4 + r;
                    int k  = nk * 16 + (l & 15);
                    dst[ch * 32 + k] = accb[q][nk][r];
                }
    } else {
        #pragma unroll
        for (int q = 0; q < 4; ++q)
            #pragma unroll
            for (int nk = 0; nk < 2; ++nk)
                #pragma unroll
                for (int r = 0; r < 4; ++r) {
                    int ch = (w * 4 + q) * 16 + lg * 4 + r;
                    int k  = nk * 16 + (l & 15);
                    atomicAdd(&wxp[(size_t)b * 8192 + k * 256 + ch], accb[q][nk][r]);
                }
    }
}

// ---------------- finalize (partial path): coalesced (k-fastest threads) ----------------
__global__ void enc_final_part(const float* __restrict__ wxp, const float* __restrict__ wsum,
                               const float* __restrict__ cw, float* __restrict__ out) {
    int i = blockIdx.x * 256 + threadIdx.x;
    int k = i & 31, c = (i >> 5) & 255, b = i >> 13;
    const float* p = wxp + (size_t)b * 16 * 8192 + c * 32 + k;
    float s = 0.f;
    #pragma unroll
    for (int j = 0; j < 16; ++j) s += p[(size_t)j * 8192];
    out[(size_t)b * 8192 + k * 256 + c] = s - wsum[b * 32 + k] * cw[k * 256 + c];
}
__global__ void enc_final_atomic(const float* __restrict__ wx, const float* __restrict__ wsum,
                                 const float* __restrict__ cw, float* __restrict__ out) {
    int i = blockIdx.x * 256 + threadIdx.x;
    int c = i & 255, k = (i >> 8) & 31, b = i >> 13;
    out[i] = wx[i] - wsum[b * 32 + k] * cw[k * 256 + c];
}

extern "C" void kernel_launch(void* const* d_in, const int* in_sizes, int n_in,
                              void* d_out, int out_size, void* d_ws, size_t ws_size,
                              hipStream_t stream) {
    (void)in_sizes; (void)n_in; (void)out_size;
    const float* x     = (const float*)d_in[0];
    const float* cw    = (const float*)d_in[1];
    const float* scale = (const float*)d_in[2];
    float* out = (float*)d_out;
    float* wsf = (float*)d_ws;

    const size_t need = (size_t)(4194304 + 1024 + 128 + 4096) * 4;
    const int use_partials = (ws_size >= need) ? 1 : 0;

    float *wxp, *wsum, *abp4;
    u16* cwh;
    if (use_partials) {
        wxp  = wsf;                        // 4194304 f32 (512 block tiles, [ch][k])
        wsum = wsf + 4194304;              // 1024 f32
        abp4 = wsf + 4195328;              // 128 f32
        cwh  = (u16*)(wsf + 4195456);      // 8192 u16
        (void)hipMemsetAsync(wsum, 0, 1024 * sizeof(float), stream);
    } else {
        wxp  = wsf;                        // 262144 f32
        wsum = wsf + 262144;               // 1024 f32
        abp4 = wsf + 263168;               // 128 f32
        cwh  = (u16*)(wsf + 263296);       // 8192 u16
        (void)hipMemsetAsync(d_ws, 0, 263168 * sizeof(float), stream);
    }

    hipLaunchKernelGGL(enc_prep, dim3(1),   dim3(256), 0, stream, cw, scale, abp4, cwh);
    hipLaunchKernelGGL(enc_main, dim3(512), dim3(256), 0, stream, x, cwh, abp4, wxp, wsum, use_partials);
    if (use_partials)
        hipLaunchKernelGGL(enc_final_part,   dim3(1024), dim3(256), 0, stream, wxp, wsum, cw, out);
    else
        hipLaunchKernelGGL(enc_final_atomic, dim3(1024), dim3(256), 0, stream, wxp, wsum, cw, out);
}